// Round 1
// 166.123 us; speedup vs baseline: 1.0076x; 1.0076x over previous
//
#include <hip/hip_runtime.h>

// Segmented gather: out[t] = req_to_token[req_pool_indices[r]*MAXLEN +
//                                         kv_start_idx[r] + (t - kv_indptr[r])]
// where r is the segment owning t (kv_indptr[r] <= t < kv_indptr[r+1]).
//
// Structure exploited:
//   - NREQ == 64 == wavefront size: lane l caches segment l's metadata in
//     registers; the block's owning segment r0 is found with ONE __ballot
//     (indptr is sorted), not a binary search. No LDS, no __syncthreads.
//   - Segment lengths are >= 1024, block spans SPAN=2048 positions => at most
//     2 boundaries (3 segments) intersect a block. Proof: end0 = indptr[r0+1]
//     > t_blk, end1 >= end0+1024, end2 >= end0+2048 > t_blk+SPAN-1, so every
//     element in the block lies in segment r0, r0+1, or r0+2.
//   - Per-segment fused offset gbase[r] = pool_row*MAXLEN + start - indptr[r],
//     so the gather is req_to_token[gbase[r] + t], contiguous in t.

#define NREQ   64
#define MAXLEN 16384
#define TPB    256
#define EPT    8              // elements per thread
#define SPAN   (TPB * EPT)    // 2048 output positions per block

__global__ __launch_bounds__(TPB) void kv_gather_kernel(
    const int* __restrict__ req_to_token,
    const int* __restrict__ req_pool_indices,
    const int* __restrict__ kv_indptr,
    const int* __restrict__ kv_start_idx,
    int* __restrict__ out,
    int total)
{
    const int tid  = threadIdx.x;
    const int lane = tid & 63;

    // Per-lane segment metadata: 4 independent global loads, one round trip.
    const int ip  = kv_indptr[lane];         // indptr[l]
    const int ip1 = kv_indptr[lane + 1];     // indptr[l+1]  (lane 63 -> indptr[64] = total)
    const int gb  = req_pool_indices[lane] * MAXLEN + kv_start_idx[lane] - ip;

    const int t_blk = blockIdx.x * SPAN;

    // r0 = largest r with indptr[r] <= t_blk  (indptr sorted ascending,
    // indptr[0] = 0 guarantees popc >= 1).
    const unsigned long long m = __ballot(ip <= t_blk);
    const int r0 = __popcll(m) - 1;

    // Segment ends / bases for the <=3 segments touching this block.
    // min-clamp: out-of-range lanes resolve to indptr[64] = total, which acts
    // as a correct "no further segment" sentinel (t >= total never occurs).
    const int i1 = min(r0 + 1, NREQ - 1);
    const int i2 = min(r0 + 2, NREQ - 1);
    const int end0 = __shfl(ip1, r0);   // indptr[r0+1]
    const int end1 = __shfl(ip1, i1);   // indptr[r0+2] (or total)
    const int end2 = __shfl(ip1, i2);   // indptr[r0+3] (or total)
    const int g0   = __shfl(gb,  r0);
    const int g1   = __shfl(gb,  i1);   // only used when t >= end0 (< total)
    const int g2   = __shfl(gb,  i2);   // only used when t >= end1 (< total)

    const int t0 = t_blk + tid * EPT;
    if (t0 >= total) return;

    #pragma unroll
    for (int q = 0; q < EPT; q += 4) {
        const int tq = t0 + q;
        const int s  = (tq >= end0) + (tq >= end1);        // segment of tq
        const int g  = (s == 0) ? g0   : ((s == 1) ? g1   : g2);
        const int eq = (s == 0) ? end0 : ((s == 1) ? end1 : end2);
        if (tq + 3 < eq) {
            // whole quad inside one segment (eq <= total, so bounds are safe);
            // 4 independent loads, issued together in one round trip.
            int4 v;
            v.x = req_to_token[g + tq];
            v.y = req_to_token[g + tq + 1];
            v.z = req_to_token[g + tq + 2];
            v.w = req_to_token[g + tq + 3];
            *reinterpret_cast<int4*>(out + tq) = v;        // tq % 4 == 0: 16B aligned
        } else {
            // quad crosses a boundary or the end of the output
            const int tend = min(tq + 4, total);
            for (int t = tq; t < tend; ++t) {
                const int ss = (t >= end0) + (t >= end1);
                const int gg = (ss == 0) ? g0 : ((ss == 1) ? g1 : g2);
                out[t] = req_to_token[gg + t];
            }
        }
    }
}

extern "C" void kernel_launch(void* const* d_in, const int* in_sizes, int n_in,
                              void* d_out, int out_size, void* d_ws, size_t ws_size,
                              hipStream_t stream) {
    const int* req_to_token     = (const int*)d_in[0];
    const int* req_pool_indices = (const int*)d_in[1];
    // d_in[2] = page_kernel_lens (unused; lens are implicit in kv_indptr)
    const int* kv_indptr        = (const int*)d_in[3];
    const int* kv_start_idx     = (const int*)d_in[4];
    int* out = (int*)d_out;

    const int total  = out_size;
    const int blocks = (total + SPAN - 1) / SPAN;   // 144 blocks @ total ~295K -> single CU round
    kv_gather_kernel<<<blocks, TPB, 0, stream>>>(
        req_to_token, req_pool_indices, kv_indptr, kv_start_idx, out, total);
}